// Round 10
// baseline (49.304 us; speedup 1.0000x reference)
//
#include <hip/hip_runtime.h>

#define WPTS 801
#define ROWS 4
#define NT 256

typedef _Float16 h2 __attribute__((ext_vector_type(2)));
typedef unsigned int u32;

struct c2 { float x, y; };

__device__ __forceinline__ c2 c_addc(c2 a, c2 b) { return {a.x + b.x, a.y + b.y}; }
__device__ __forceinline__ c2 c_subc(c2 a, c2 b) { return {a.x - b.x, a.y - b.y}; }
__device__ __forceinline__ c2 c_divc(c2 a, c2 b) {
    float inv = 1.0f / (b.x * b.x + b.y * b.y);
    return {(a.x * b.x + a.y * b.y) * inv, (a.y * b.x - a.x * b.y) * inv};
}

// Pack two f32 into f16x2 (v_cvt_pkrtz_f16_f32) viewed as u32.
__device__ __forceinline__ u32 pk2(float a, float b) {
    return __builtin_bit_cast(u32, __builtin_amdgcn_cvt_pkrtz(a, b));
}
__device__ __forceinline__ u32 pkc(float v) { return pk2(v, v); }

// Forced packed-f16 math (VOP3P, full-rate, 2 values/inst). All operands VGPR.
#define PKFMA16(d, a, b, c) asm("v_pk_fma_f16 %0, %1, %2, %3" : "=v"(d) : "v"(a), "v"(b), "v"(c))
#define PKMUL16(d, a, b)    asm("v_pk_mul_f16 %0, %1, %2"     : "=v"(d) : "v"(a), "v"(b))

__global__ __launch_bounds__(NT)
void kla_tmm_kernel(const float* __restrict__ d_phys,
                    const float* __restrict__ nSi_f,
                    const float* __restrict__ nSiO2_f,
                    const float* __restrict__ nSi3N4_f,
                    const float* __restrict__ lam,
                    float* __restrict__ out,
                    int B)
{
    const int nRowBlks = (B + ROWS - 1) / ROWS;
    const int t = blockIdx.x * NT + threadIdx.x;
    if (t >= nRowBlks * WPTS) return;

    const int w = t % WPTS;
    const int row0 = (t / WPTS) * ROWS;
    const int nrows = min(ROWS, B - row0);

    // ---- Layout-robust complex reads (same detection as passing r2-r9) ----
    const bool ilv = (nSiO2_f[1] == 0.0f);
    float nSx, nSy, nOx, nOy, nNx, nNy;
    if (ilv) {
        nSx = nSi_f[2 * w];    nSy = nSi_f[2 * w + 1];
        nOx = nSiO2_f[2 * w];  nOy = nSiO2_f[2 * w + 1];
        nNx = nSi3N4_f[2 * w]; nNy = nSi3N4_f[2 * w + 1];
    } else {
        nSx = nSi_f[w];    nSy = 0.0f;
        nOx = nSiO2_f[w];  nOy = 0.0f;
        nNx = nSi3N4_f[w]; nNy = 0.0f;
    }

    const bool realn = (nOy == 0.0f) && (nNy == 0.0f) && (nSy == 0.0f);

    if (realn && nrows == ROWS) {
        // ==== real-n fast path: v-basis; f32 phase reduction; poly+mix in
        //      FORCED v_pk_*_f16 (2 rows per instruction). Same math as the
        //      passing r7 (v-basis) + r9 (f16 poly, parity cancels in R). ====
        const float rlam = __builtin_amdgcn_rcpf(lam[w]);
        const float kO2 = 2.0f * nOx * rlam;                 // half-revolutions/nm
        const float kN2 = 2.0f * nNx * rlam;
        const float gAO = __builtin_amdgcn_rcpf(nOx);        // Air |SiO2 : 1/nO
        const float gON = nOx * __builtin_amdgcn_rcpf(nNx);  // SiO2|Si3N4: nO/nN
        const float gNO = nNx * gAO;                         // Si3N4|SiO2: nN/nO

        const u32 gAOp = pkc(gAO), gONp = pkc(gON), gNOp = pkc(gNO);
        // sin(pi t) deg-7 / cos(pi t) deg-6 minimax-ish Taylor, |t|<=0.5
        const u32 cA1 = pkc( 3.14159265f);
        const u32 cA3 = pkc(-5.16771278f);
        const u32 cA5 = pkc( 2.55016404f);
        const u32 cA7 = pkc(-0.59926453f);
        const u32 cC2 = pkc(-4.93480220f);
        const u32 cC4 = pkc( 4.05871213f);
        const u32 cC6 = pkc(-1.33526277f);
        const u32 cOne  = pkc(1.0f);
        const u32 cNeg1 = pkc(-1.0f);
        const u32 v0i = pkc(nOx), v1i = pkc(nSx), zz = pkc(0.0f);

        const float* base = d_phys + (size_t)row0 * 7;
        float* orow = out + (size_t)row0 * WPTS + w;

        #pragma unroll
        for (int pr = 0; pr < ROWS; pr += 2) {
            const float* dA = base + (size_t)pr * 7;
            const float* dB = dA + 7;

            u32 v0x = v0i, v0y = zz, v1x = v1i, v1y = zz;

            #pragma unroll
            for (int i = 7; i >= 1; --i) {
                const float kk = (i & 1) ? kO2 : kN2;
                const u32 g = (i == 1) ? gAOp : ((i & 1) ? gNOp : gONp);

                const float nuA = dA[i - 1] * kk;
                const float nuB = dB[i - 1] * kk;
                const float tA = nuA - __builtin_rintf(nuA);
                const float tB = nuB - __builtin_rintf(nuB);
                const u32 tt = pk2(tA, tB);

                u32 q, ps, s, pc, ns;
                PKMUL16(q, tt, tt);
                PKFMA16(ps, q, cA7, cA5);
                PKFMA16(ps, q, ps, cA3);
                PKFMA16(ps, q, ps, cA1);
                PKMUL16(s, tt, ps);                 // sin(pi t)  (joint sign dropped)
                PKFMA16(pc, q, cC6, cC4);
                PKFMA16(pc, q, pc, cC2);
                PKFMA16(pc, q, pc, cOne);           // cos(pi t)
                PKMUL16(ns, s, cNeg1);              // -s

                u32 gc, gs, gns;
                PKMUL16(gc, g, pc);
                PKMUL16(gs, g, s);
                PKMUL16(gns, g, ns);

                // v0' = g*(c v0 - i s v1) ; v1' = c v1 - i s v0
                u32 m0, m1, m2, m3, nv0x, nv0y, nv1x, nv1y;
                PKMUL16(m0, gs, v1y);  PKFMA16(nv0x, gc, v0x, m0);
                PKMUL16(m1, gns, v1x); PKFMA16(nv0y, gc, v0y, m1);
                PKMUL16(m2, s, v0y);   PKFMA16(nv1x, pc, v1x, m2);
                PKMUL16(m3, ns, v0x);  PKFMA16(nv1y, pc, v1y, m3);
                v0x = nv0x; v0y = nv0y; v1x = nv1x; v1y = nv1y;
            }

            // Epilogue in f32: R = |v0-v1|^2 / |v0+v1|^2  (per packed lane)
            const h2 h0x = __builtin_bit_cast(h2, v0x);
            const h2 h0y = __builtin_bit_cast(h2, v0y);
            const h2 h1x = __builtin_bit_cast(h2, v1x);
            const h2 h1y = __builtin_bit_cast(h2, v1y);
            {
                const float p0x = (float)h0x.x, p0y = (float)h0y.x;
                const float p1x = (float)h1x.x, p1y = (float)h1y.x;
                const float ax = p0x - p1x, ay = p0y - p1y;
                const float bx = p0x + p1x, by = p0y + p1y;
                const float num = ax * ax + ay * ay;
                const float den = bx * bx + by * by;
                orow[(size_t)pr * WPTS] = num * __builtin_amdgcn_rcpf(den);
            }
            {
                const float p0x = (float)h0x.y, p0y = (float)h0y.y;
                const float p1x = (float)h1x.y, p1y = (float)h1y.y;
                const float ax = p0x - p1x, ay = p0y - p1y;
                const float bx = p0x + p1x, by = p0y + p1y;
                const float num = ax * ax + ay * ay;
                const float den = bx * bx + by * by;
                orow[(size_t)(pr + 1) * WPTS] = num * __builtin_amdgcn_rcpf(den);
            }
        }
    } else {
        // ======== general complex path (round-2 code, known correct) ========
        const float k0 = 6.28318530717958647692f / lam[w];
        const c2 nA = {1.0f, 0.0f};
        const c2 nO = {nOx, nOy}, nN = {nNx, nNy}, nS = {nSx, nSy};
        const c2 rAO  = c_divc(c_subc(nA, nO), c_addc(nA, nO));
        const c2 rON  = c_divc(c_subc(nO, nN), c_addc(nO, nN));
        const c2 rNO  = {-rON.x, -rON.y};
        const c2 rOSi = c_divc(c_subc(nO, nS), c_addc(nO, nS));
        const c2 kO = {k0 * nO.x, k0 * nO.y};
        const c2 kN = {k0 * nN.x, k0 * nN.y};

        for (int rr = 0; rr < nrows; ++rr) {
            const int row = row0 + rr;
            const float* dd = d_phys + (size_t)row * 7;

            c2 u0 = {1.0f, 0.0f};
            c2 u1 = rOSi;

            #pragma unroll
            for (int i = 7; i >= 1; --i) {
                const float d = dd[i - 1];
                const c2 kk = (i & 1) ? kO : kN;
                const float alpha = kk.x * d;
                const float beta  = kk.y * d;
                float s, c;
                __sincosf(alpha, &s, &c);
                const float ep = __expf(beta);
                const float em = __expf(-beta);

                c2 v;
                v.x = ep * (u0.x * c + u0.y * s);
                v.y = ep * (u0.y * c - u0.x * s);
                u0 = v;
                v.x = em * (u1.x * c - u1.y * s);
                v.y = em * (u1.y * c + u1.x * s);
                u1 = v;

                const c2 ri = (i == 1) ? rAO : ((i & 1) ? rNO : rON);
                c2 w0, w1;
                w0.x = u0.x + ri.x * u1.x - ri.y * u1.y;
                w0.y = u0.y + ri.x * u1.y + ri.y * u1.x;
                w1.x = u1.x + ri.x * u0.x - ri.y * u0.y;
                w1.y = u1.y + ri.x * u0.y + ri.y * u0.x;
                u0 = w0; u1 = w1;
            }

            out[(size_t)row * WPTS + w] =
                (u1.x * u1.x + u1.y * u1.y) / (u0.x * u0.x + u0.y * u0.y);
        }
    }
}

extern "C" void kernel_launch(void* const* d_in, const int* in_sizes, int n_in,
                              void* d_out, int out_size, void* d_ws, size_t ws_size,
                              hipStream_t stream) {
    const float* d_phys  = (const float*)d_in[0];
    const float* nSi     = (const float*)d_in[1];
    const float* nSiO2   = (const float*)d_in[2];
    const float* nSi3N4  = (const float*)d_in[3];
    const float* lam     = (const float*)d_in[4];
    float* out = (float*)d_out;

    const int B = in_sizes[0] / 7;
    const int nRowBlks = (B + ROWS - 1) / ROWS;
    const int nTasks = nRowBlks * WPTS;
    const int grid = (nTasks + NT - 1) / NT;

    kla_tmm_kernel<<<grid, NT, 0, stream>>>(
        d_phys, nSi, nSiO2, nSi3N4, lam, out, B);
}

// Round 11
// 47.802 us; speedup vs baseline: 1.0314x; 1.0314x over previous
//
#include <hip/hip_runtime.h>

#define WPTS 801
#define ROWS 4
#define NT 256

struct c2 { float x, y; };

__device__ __forceinline__ c2 c_addc(c2 a, c2 b) { return {a.x + b.x, a.y + b.y}; }
__device__ __forceinline__ c2 c_subc(c2 a, c2 b) { return {a.x - b.x, a.y - b.y}; }
__device__ __forceinline__ c2 c_divc(c2 a, c2 b) {
    float inv = 1.0f / (b.x * b.x + b.y * b.y);
    return {(a.x * b.x + a.y * b.y) * inv, (a.y * b.x - a.x * b.y) * inv};
}

__global__ __launch_bounds__(NT, 4)   // allow up to 128 VGPR/wave: room for ILP
void kla_tmm_kernel(const float* __restrict__ d_phys,
                    const float* __restrict__ nSi_f,
                    const float* __restrict__ nSiO2_f,
                    const float* __restrict__ nSi3N4_f,
                    const float* __restrict__ lam,
                    float* __restrict__ out,
                    int B)
{
    const int nRowBlks = (B + ROWS - 1) / ROWS;
    const int t = blockIdx.x * NT + threadIdx.x;
    if (t >= nRowBlks * WPTS) return;

    const int w = t % WPTS;
    const int row0 = (t / WPTS) * ROWS;
    const int nrows = min(ROWS, B - row0);

    // ---- Layout-robust complex reads (same detection as passing r2-r10) ----
    const bool ilv = (nSiO2_f[1] == 0.0f);
    float nSx, nSy, nOx, nOy, nNx, nNy;
    if (ilv) {
        nSx = nSi_f[2 * w];    nSy = nSi_f[2 * w + 1];
        nOx = nSiO2_f[2 * w];  nOy = nSiO2_f[2 * w + 1];
        nNx = nSi3N4_f[2 * w]; nNy = nSi3N4_f[2 * w + 1];
    } else {
        nSx = nSi_f[w];    nSy = 0.0f;
        nOx = nSiO2_f[w];  nOy = 0.0f;
        nNx = nSi3N4_f[w]; nNy = 0.0f;
    }

    const bool realn = (nOy == 0.0f) && (nNy == 0.0f) && (nSy == 0.0f);

    if (realn && nrows == ROWS) {
        // ==== real-n fast path (r7 math, PHASE-SPLIT for ILP) ====
        // Phase A: all 28 nu + 56 sincos (mutually independent).
        // Phase B: 4 independent chains, serial depth only ~3 ops/layer.
        const float rlam = __builtin_amdgcn_rcpf(lam[w]);
        const float kOr = nOx * rlam;                        // rev/nm, SiO2 (odd layers)
        const float kNr = nNx * rlam;                        // rev/nm, Si3N4 (even layers)
        const float gAO = __builtin_amdgcn_rcpf(nOx);        // Air |SiO2 : 1/nO
        const float gON = nOx * __builtin_amdgcn_rcpf(nNx);  // SiO2|Si3N4: nO/nN
        const float gNO = nNx * gAO;                         // Si3N4|SiO2: nN/nO

        const float* base = d_phys + (size_t)row0 * 7;
        float* orow = out + (size_t)row0 * WPTS + w;

        // ---- Phase A: bulk sincos (fully independent; fills trans pipe) ----
        float sv[ROWS][7], cf[ROWS][7];
        #pragma unroll
        for (int r = 0; r < ROWS; ++r) {
            #pragma unroll
            for (int j = 0; j < 7; ++j) {   // j = layer-1; even j -> SiO2
                const float kk = (j & 1) ? kNr : kOr;
                const float nu = base[r * 7 + j] * kk;
                sv[r][j] = __builtin_amdgcn_sinf(nu);   // sin(2*pi*nu)
                cf[r][j] = __builtin_amdgcn_cosf(nu);
            }
        }

        // ---- Phase B: 4 independent short chains ----
        #pragma unroll
        for (int r = 0; r < ROWS; ++r) {
            float v0x = nOx, v0y = 0.0f;
            float v1x = nSx, v1y = 0.0f;

            #pragma unroll
            for (int j = 6; j >= 0; --j) {  // layer i=j+1, from 7 down to 1
                const float s = sv[r][j];
                const float c = cf[r][j];
                const float g = (j == 0) ? gAO : ((j & 1) ? gON : gNO);
                // phase mix: v0' = c v0 - i s v1 ; v1' = c v1 - i s v0
                const float w0x = v0x * c + v1y * s;
                const float w0y = v0y * c - v1x * s;
                const float w1x = v1x * c + v0y * s;
                const float w1y = v1y * c - v0x * s;
                // interface diagonal: v0 *= g (v1 factor folds into global scale)
                v0x = w0x * g;
                v0y = w0y * g;
                v1x = w1x;
                v1y = w1y;
            }

            // R = |v0-v1|^2 / |v0+v1|^2
            const float ax = v0x - v1x, ay = v0y - v1y;
            const float bx = v0x + v1x, by = v0y + v1y;
            const float num = ax * ax + ay * ay;
            const float den = bx * bx + by * by;
            orow[(size_t)r * WPTS] = num * __builtin_amdgcn_rcpf(den);
        }
    } else {
        // ======== general complex path (round-2 code, known correct) ========
        const float k0 = 6.28318530717958647692f / lam[w];
        const c2 nA = {1.0f, 0.0f};
        const c2 nO = {nOx, nOy}, nN = {nNx, nNy}, nS = {nSx, nSy};
        const c2 rAO  = c_divc(c_subc(nA, nO), c_addc(nA, nO));
        const c2 rON  = c_divc(c_subc(nO, nN), c_addc(nO, nN));
        const c2 rNO  = {-rON.x, -rON.y};
        const c2 rOSi = c_divc(c_subc(nO, nS), c_addc(nO, nS));
        const c2 kO = {k0 * nO.x, k0 * nO.y};
        const c2 kN = {k0 * nN.x, k0 * nN.y};

        for (int rr = 0; rr < nrows; ++rr) {
            const int row = row0 + rr;
            const float* dd = d_phys + (size_t)row * 7;

            c2 u0 = {1.0f, 0.0f};
            c2 u1 = rOSi;

            #pragma unroll
            for (int i = 7; i >= 1; --i) {
                const float d = dd[i - 1];
                const c2 kk = (i & 1) ? kO : kN;
                const float alpha = kk.x * d;
                const float beta  = kk.y * d;
                float s, c;
                __sincosf(alpha, &s, &c);
                const float ep = __expf(beta);
                const float em = __expf(-beta);

                c2 v;
                v.x = ep * (u0.x * c + u0.y * s);
                v.y = ep * (u0.y * c - u0.x * s);
                u0 = v;
                v.x = em * (u1.x * c - u1.y * s);
                v.y = em * (u1.y * c + u1.x * s);
                u1 = v;

                const c2 ri = (i == 1) ? rAO : ((i & 1) ? rNO : rON);
                c2 w0, w1;
                w0.x = u0.x + ri.x * u1.x - ri.y * u1.y;
                w0.y = u0.y + ri.x * u1.y + ri.y * u1.x;
                w1.x = u1.x + ri.x * u0.x - ri.y * u0.y;
                w1.y = u1.y + ri.x * u0.y + ri.y * u0.x;
                u0 = w0; u1 = w1;
            }

            out[(size_t)row * WPTS + w] =
                (u1.x * u1.x + u1.y * u1.y) / (u0.x * u0.x + u0.y * u0.y);
        }
    }
}

extern "C" void kernel_launch(void* const* d_in, const int* in_sizes, int n_in,
                              void* d_out, int out_size, void* d_ws, size_t ws_size,
                              hipStream_t stream) {
    const float* d_phys  = (const float*)d_in[0];
    const float* nSi     = (const float*)d_in[1];
    const float* nSiO2   = (const float*)d_in[2];
    const float* nSi3N4  = (const float*)d_in[3];
    const float* lam     = (const float*)d_in[4];
    float* out = (float*)d_out;

    const int B = in_sizes[0] / 7;
    const int nRowBlks = (B + ROWS - 1) / ROWS;
    const int nTasks = nRowBlks * WPTS;
    const int grid = (nTasks + NT - 1) / NT;

    kla_tmm_kernel<<<grid, NT, 0, stream>>>(
        d_phys, nSi, nSiO2, nSi3N4, lam, out, B);
}